// Round 3
// baseline (2076.882 us; speedup 1.0000x reference)
//
#include <hip/hip_runtime.h>
#include <hip/hip_fp16.h>

typedef _Float16 f16;
typedef __attribute__((ext_vector_type(8))) _Float16 f16x8;
typedef __attribute__((ext_vector_type(4))) _Float16 f16x4;
typedef __attribute__((ext_vector_type(4))) float f32x4;
typedef __attribute__((ext_vector_type(4))) float float4v;

// Shapes: x[512,256,256], carry0[256,256], Wi[256,768], bi[768],
//         Wh[256,768], bhn[256], Wo[256,16], bo[16] -> out[512,256,16] f32

static __device__ __forceinline__ float sigm(float x) {
  return __builtin_amdgcn_rcpf(1.0f + __expf(-x));
}
static __device__ __forceinline__ float tanh_fast(float x) {
  float e = __expf(2.0f * x);
  return 1.0f - 2.0f * __builtin_amdgcn_rcpf(e + 1.0f);
}

// ---------------- K0: transpose+convert Wi -> WiT[768][256] f16 -------------
__global__ void k_prep_wit(const float* __restrict__ Wi, f16* __restrict__ WiT) {
  int n = blockIdx.x;   // 0..767
  int k = threadIdx.x;  // 0..255
  WiT[n * 256 + k] = (f16)Wi[(size_t)k * 768 + n];
}

// ---------------- K1: gx = x @ Wi + bi  (fp16 MFMA, 128x128 tile) -----------
__global__ __launch_bounds__(256, 4) void k_gemm_gx(
    const float* __restrict__ x, const f16* __restrict__ WiT,
    const float* __restrict__ bi, f16* __restrict__ gx) {
  __shared__ f16 As[128 * 64];  // [row][k] fp16, XOR-swizzled
  __shared__ f16 Bs[128 * 64];  // [n][k]  fp16 (B transposed), XOR-swizzled
  const int tid = threadIdx.x;
  const int lane = tid & 63;
  const int wave = tid >> 6;
  const int wm = wave >> 1, wn = wave & 1;
  const int m0 = blockIdx.y * 128;
  const int n0 = blockIdx.x * 128;

  f32x4 acc[4][4] = {};

  for (int ks = 0; ks < 4; ++ks) {
    const int k0 = ks * 64;
    // stage A: 128 rows x 64 f32 -> f16 (coalesced float4 reads)
#pragma unroll
    for (int i = 0; i < 8; ++i) {
      int c = i * 256 + tid;  // 0..2047 8B-chunks (16 per 128B row)
      int row = c >> 4, cx = c & 15;
      float4v v = *reinterpret_cast<const float4v*>(
          x + (size_t)(m0 + row) * 256 + k0 + cx * 4);
      f16x4 hv;
      hv[0] = (f16)v[0]; hv[1] = (f16)v[1]; hv[2] = (f16)v[2]; hv[3] = (f16)v[3];
      int boff = row * 128 + ((cx * 8) ^ ((row & 7) << 4));
      *reinterpret_cast<f16x4*>(reinterpret_cast<char*>(As) + boff) = hv;
    }
    // stage B from WiT (already f16): 128 n-rows x 64 k = 1024 16B-chunks
#pragma unroll
    for (int i = 0; i < 4; ++i) {
      int c = i * 256 + tid;  // 0..1023
      int n = c >> 3, cx = c & 7;  // 8 chunks per 128B row
      f16x8 v = *reinterpret_cast<const f16x8*>(
          WiT + (size_t)(n0 + n) * 256 + k0 + cx * 8);
      int boff = n * 128 + ((cx * 16) ^ ((n & 7) << 4));
      *reinterpret_cast<f16x8*>(reinterpret_cast<char*>(Bs) + boff) = v;
    }
    __syncthreads();
#pragma unroll
    for (int kt = 0; kt < 2; ++kt) {
      const int kb = kt * 64 + ((lane >> 4) << 4);  // byte offset along K
      f16x8 a[4], b[4];
#pragma unroll
      for (int mt = 0; mt < 4; ++mt) {
        int r = wm * 64 + mt * 16 + (lane & 15);
        a[mt] = *reinterpret_cast<const f16x8*>(
            reinterpret_cast<const char*>(As) + r * 128 + (kb ^ ((r & 7) << 4)));
      }
#pragma unroll
      for (int nt = 0; nt < 4; ++nt) {
        int r = wn * 64 + nt * 16 + (lane & 15);
        b[nt] = *reinterpret_cast<const f16x8*>(
            reinterpret_cast<const char*>(Bs) + r * 128 + (kb ^ ((r & 7) << 4)));
      }
#pragma unroll
      for (int mt = 0; mt < 4; ++mt)
#pragma unroll
        for (int nt = 0; nt < 4; ++nt)
          acc[mt][nt] = __builtin_amdgcn_mfma_f32_16x16x32_f16(
              a[mt], b[nt], acc[mt][nt], 0, 0, 0);
    }
    __syncthreads();
  }
  // epilogue: + bi, cvt f16, store
  float biv[4];
#pragma unroll
  for (int nt = 0; nt < 4; ++nt) biv[nt] = bi[n0 + wn * 64 + nt * 16 + (lane & 15)];
#pragma unroll
  for (int mt = 0; mt < 4; ++mt)
#pragma unroll
    for (int nt = 0; nt < 4; ++nt)
#pragma unroll
      for (int r = 0; r < 4; ++r) {
        size_t row = (size_t)m0 + wm * 64 + mt * 16 + ((lane >> 4) << 2) + r;
        int col = n0 + wn * 64 + nt * 16 + (lane & 15);
        gx[row * 768 + col] = (f16)(acc[mt][nt][r] + biv[nt]);
      }
}

// ---------------- K2: GRU scan, 16 blocks x 16 waves (1024 thr) -------------
// block = 16 batch rows; wave owns 16 H-cols per gate. Wh r,z gates in VGPR
// frags (64 VGPR), n gate in LDS frags. h double-buffered in LDS (XOR
// swizzle). gx for step t+1 prefetched into registers during step t.
// carries are written into the consumed r-gate slot of gx.
__global__ __launch_bounds__(1024, 4) void k_scan(
    const float* __restrict__ carry0, const float* __restrict__ Wh,
    const float* __restrict__ bhn, f16* __restrict__ gx) {
  __shared__ f16 nfr[16 * 8 * 64 * 8];  // 131072 B: n-gate B-frags
  __shared__ f16 hb[2 * 16 * 256];      // 16384 B: h double buffer
  const int tid = threadIdx.x;
  const int lane = tid & 63;
  const int wave = tid >> 6;  // 0..15
  const int l15 = lane & 15, l4 = lane >> 4;
  const int r0 = blockIdx.x * 16;

  // Wh gates r(0), z(1) -> register fragments (B-layout: B[k][j], j=lane&15,
  // k = kt*32 + (lane>>4)*8 + e)
  f16x8 whf[2][8];
#pragma unroll
  for (int g = 0; g < 2; ++g) {
    const int col = g * 256 + wave * 16 + l15;
#pragma unroll
    for (int kt = 0; kt < 8; ++kt)
#pragma unroll
      for (int e = 0; e < 8; ++e)
        whf[g][kt][e] = (f16)Wh[(size_t)(kt * 32 + l4 * 8 + e) * 768 + col];
  }
  // n gate -> LDS fragments (frag-linear: conflict-free b128)
  {
    const int col = 512 + wave * 16 + l15;
#pragma unroll
    for (int kt = 0; kt < 8; ++kt) {
      f16x8 v;
#pragma unroll
      for (int e = 0; e < 8; ++e)
        v[e] = (f16)Wh[(size_t)(kt * 32 + l4 * 8 + e) * 768 + col];
      *reinterpret_cast<f16x8*>(reinterpret_cast<char*>(nfr) +
                                (wave * 8 + kt) * 1024 + lane * 16) = v;
    }
  }
  const float bh = bhn[wave * 16 + l15];

  // init h (registers hold the D-layout elements; LDS holds full row-major)
  float hcur[4];
#pragma unroll
  for (int j = 0; j < 4; ++j) {
    int row = l4 * 4 + j;
    int col = wave * 16 + l15;
    float h = carry0[(size_t)(r0 + row) * 256 + col];
    hcur[j] = h;
    int boff = row * 512 + ((col * 2) ^ ((row & 7) << 4));
    *reinterpret_cast<f16*>(reinterpret_cast<char*>(hb) + boff) = (f16)h;
  }
  __syncthreads();

  f16* gxbase = gx + (size_t)r0 * 768;

  // preload gx gate values for t=0
  f16 gv[3][4];
#pragma unroll
  for (int g = 0; g < 3; ++g)
#pragma unroll
    for (int j = 0; j < 4; ++j)
      gv[g][j] = gxbase[(size_t)(l4 * 4 + j) * 768 + g * 256 + wave * 16 + l15];

  for (int t = 0; t < 512; ++t) {
    const int cur = (t & 1) * 8192;
    const int nxt = 8192 - cur;

    // prefetch NEXT step's gx values (full step of latency cover)
    const f16* gnx = gxbase + (t < 511 ? (size_t)256 * 768 : 0);
    f16 gvn[3][4];
#pragma unroll
    for (int g = 0; g < 3; ++g)
#pragma unroll
      for (int j = 0; j < 4; ++j)
        gvn[g][j] = gnx[(size_t)(l4 * 4 + j) * 768 + g * 256 + wave * 16 + l15];

    f32x4 acc[3] = {};
#pragma unroll
    for (int kt = 0; kt < 8; ++kt) {
      const int kb = kt * 64 + l4 * 16;
      const int rr = l15;
      f16x8 a = *reinterpret_cast<const f16x8*>(
          reinterpret_cast<const char*>(hb) + cur + rr * 512 + (kb ^ ((rr & 7) << 4)));
      f16x8 nb = *reinterpret_cast<const f16x8*>(
          reinterpret_cast<const char*>(nfr) + (wave * 8 + kt) * 1024 + lane * 16);
      acc[0] = __builtin_amdgcn_mfma_f32_16x16x32_f16(a, whf[0][kt], acc[0], 0, 0, 0);
      acc[1] = __builtin_amdgcn_mfma_f32_16x16x32_f16(a, whf[1][kt], acc[1], 0, 0, 0);
      acc[2] = __builtin_amdgcn_mfma_f32_16x16x32_f16(a, nb, acc[2], 0, 0, 0);
    }
    // elementwise GRU + write h (LDS next buf, and carries into r-gate slot)
    {
      const int col = wave * 16 + l15;
#pragma unroll
      for (int j = 0; j < 4; ++j) {
        const int row = l4 * 4 + j;
        float rg = sigm((float)gv[0][j] + acc[0][j]);
        float zg = sigm((float)gv[1][j] + acc[1][j]);
        float ng = tanh_fast((float)gv[2][j] + rg * (acc[2][j] + bh));
        float h = ng + zg * (hcur[j] - ng);
        hcur[j] = h;
        f16 hh = (f16)h;
        int boff = nxt + row * 512 + ((col * 2) ^ ((row & 7) << 4));
        *reinterpret_cast<f16*>(reinterpret_cast<char*>(hb) + boff) = hh;
        gxbase[(size_t)row * 768 + col] = hh;  // carries (r-gate already consumed)
      }
    }
#pragma unroll
    for (int g = 0; g < 3; ++g)
#pragma unroll
      for (int j = 0; j < 4; ++j)
        gv[g][j] = gvn[g][j];
    gxbase += (size_t)256 * 768;
    __syncthreads();
  }
}

// ---------------- K3: head  out = [h@Wo+bo | exp(clip(h@Wo+bo))] ------------
__global__ __launch_bounds__(256) void k_head(const f16* __restrict__ gx,
                                              const float* __restrict__ Wo,
                                              const float* __restrict__ bo,
                                              float* __restrict__ out) {
  const int t = blockIdx.x;
  const int tid = threadIdx.x;
  const int lane = tid & 63;
  const int wave = tid >> 6;
  const int l15 = lane & 15, l4 = lane >> 4;

  f16x8 wof[8];
#pragma unroll
  for (int kt = 0; kt < 8; ++kt)
#pragma unroll
    for (int e = 0; e < 8; ++e)
      wof[kt][e] = (f16)Wo[(kt * 32 + l4 * 8 + e) * 16 + l15];
  float bov = bo[l15];

#pragma unroll
  for (int mi = 0; mi < 4; ++mi) {
    f32x4 acc = {};
    const size_t rbase = (size_t)(t * 256 + wave * 64 + mi * 16 + l15) * 768;
#pragma unroll
    for (int kt = 0; kt < 8; ++kt) {
      f16x8 a = *reinterpret_cast<const f16x8*>(gx + rbase + kt * 32 + l4 * 8);
      acc = __builtin_amdgcn_mfma_f32_16x16x32_f16(a, wof[kt], acc, 0, 0, 0);
    }
#pragma unroll
    for (int r = 0; r < 4; ++r) {
      int orow = wave * 64 + mi * 16 + l4 * 4 + r;
      float y = acc[r] + bov;
      if (l15 >= 8) y = __expf(fminf(fmaxf(y, -20.0f), 2.0f));
      out[((size_t)t * 256 + orow) * 16 + l15] = y;
    }
  }
}

extern "C" void kernel_launch(void* const* d_in, const int* in_sizes, int n_in,
                              void* d_out, int out_size, void* d_ws, size_t ws_size,
                              hipStream_t stream) {
  const float* x      = (const float*)d_in[0];
  const float* carry0 = (const float*)d_in[1];
  const float* Wi     = (const float*)d_in[2];
  const float* bi     = (const float*)d_in[3];
  const float* Wh     = (const float*)d_in[4];
  const float* bhn    = (const float*)d_in[5];
  const float* Wo     = (const float*)d_in[6];
  const float* bo     = (const float*)d_in[7];
  float* out = (float*)d_out;

  f16* gx  = (f16*)d_ws;                       // 512*256*768 f16 = 192 MiB
  f16* WiT = gx + (size_t)512 * 256 * 768;     // 768*256 f16

  k_prep_wit<<<dim3(768), dim3(256), 0, stream>>>(Wi, WiT);
  k_gemm_gx<<<dim3(6, 1024), dim3(256), 0, stream>>>(x, WiT, bi, gx);
  k_scan<<<dim3(16), dim3(1024), 0, stream>>>(carry0, Wh, bhn, gx);
  k_head<<<dim3(512), dim3(256), 0, stream>>>(gx, Wo, bo, out);
}

// Round 4
// 1187.568 us; speedup vs baseline: 1.7489x; 1.7489x over previous
//
#include <hip/hip_runtime.h>
#include <hip/hip_fp16.h>

typedef _Float16 f16;
typedef __attribute__((ext_vector_type(8))) _Float16 f16x8;
typedef __attribute__((ext_vector_type(4))) _Float16 f16x4;
typedef __attribute__((ext_vector_type(4))) float f32x4;
typedef __attribute__((ext_vector_type(4))) float float4v;

// Shapes: x[512,256,256], carry0[256,256], Wi[256,768], bi[768],
//         Wh[256,768], bhn[256], Wo[256,16], bo[16] -> out[512,256,16] f32
//
// gx workspace layout (scan-fragment order), f16:
//   vecidx = ((t*16 + blk)*8 + wave)*6 + (gate*2 + nt)
//   element = vecidx*256 + lane*4 + j   (j = acc reg index = row&3)
// holding value for (row = blk*16 + (lane>>4)*4 + j,
//                    col = gate*256 + wave*32 + nt*16 + (lane&15))

static __device__ __forceinline__ float sigm(float x) {
  return __builtin_amdgcn_rcpf(1.0f + __expf(-x));
}
static __device__ __forceinline__ float tanh_fast(float x) {
  float e = __expf(2.0f * x);
  return 1.0f - 2.0f * __builtin_amdgcn_rcpf(e + 1.0f);
}

// ---------------- K0: transpose+convert Wi -> WiT[768][256] f16 -------------
__global__ void k_prep_wit(const float* __restrict__ Wi, f16* __restrict__ WiT) {
  int n = blockIdx.x;   // 0..767
  int k = threadIdx.x;  // 0..255
  WiT[n * 256 + k] = (f16)Wi[(size_t)k * 768 + n];
}

// ---------------- K1: gx = x @ Wi + bi  (fp16 MFMA, 128x128 tile) -----------
__global__ __launch_bounds__(256, 4) void k_gemm_gx(
    const float* __restrict__ x, const f16* __restrict__ WiT,
    const float* __restrict__ bi, f16* __restrict__ gx) {
  __shared__ f16 As[128 * 64];  // [row][k] fp16, XOR-swizzled
  __shared__ f16 Bs[128 * 64];  // [n][k]  fp16 (B transposed), XOR-swizzled
  const int tid = threadIdx.x;
  const int lane = tid & 63;
  const int wave = tid >> 6;
  const int wm = wave >> 1, wn = wave & 1;
  const int m0 = blockIdx.y * 128;
  const int n0 = blockIdx.x * 128;

  f32x4 acc[4][4] = {};

  for (int ks = 0; ks < 4; ++ks) {
    const int k0 = ks * 64;
    // stage A: 128 rows x 64 f32 -> f16 (coalesced float4 reads)
#pragma unroll
    for (int i = 0; i < 8; ++i) {
      int c = i * 256 + tid;  // 0..2047 8B-chunks (16 per 128B row)
      int row = c >> 4, cx = c & 15;
      float4v v = *reinterpret_cast<const float4v*>(
          x + (size_t)(m0 + row) * 256 + k0 + cx * 4);
      f16x4 hv;
      hv[0] = (f16)v[0]; hv[1] = (f16)v[1]; hv[2] = (f16)v[2]; hv[3] = (f16)v[3];
      int boff = row * 128 + ((cx * 8) ^ ((row & 7) << 4));
      *reinterpret_cast<f16x4*>(reinterpret_cast<char*>(As) + boff) = hv;
    }
    // stage B from WiT (already f16): 128 n-rows x 64 k = 1024 16B-chunks
#pragma unroll
    for (int i = 0; i < 4; ++i) {
      int c = i * 256 + tid;  // 0..1023
      int n = c >> 3, cx = c & 7;  // 8 chunks per 128B row
      f16x8 v = *reinterpret_cast<const f16x8*>(
          WiT + (size_t)(n0 + n) * 256 + k0 + cx * 8);
      int boff = n * 128 + ((cx * 16) ^ ((n & 7) << 4));
      *reinterpret_cast<f16x8*>(reinterpret_cast<char*>(Bs) + boff) = v;
    }
    __syncthreads();
#pragma unroll
    for (int kt = 0; kt < 2; ++kt) {
      const int kb = kt * 64 + ((lane >> 4) << 4);  // byte offset along K
      f16x8 a[4], b[4];
#pragma unroll
      for (int mt = 0; mt < 4; ++mt) {
        int r = wm * 64 + mt * 16 + (lane & 15);
        a[mt] = *reinterpret_cast<const f16x8*>(
            reinterpret_cast<const char*>(As) + r * 128 + (kb ^ ((r & 7) << 4)));
      }
#pragma unroll
      for (int nt = 0; nt < 4; ++nt) {
        int r = wn * 64 + nt * 16 + (lane & 15);
        b[nt] = *reinterpret_cast<const f16x8*>(
            reinterpret_cast<const char*>(Bs) + r * 128 + (kb ^ ((r & 7) << 4)));
      }
#pragma unroll
      for (int mt = 0; mt < 4; ++mt)
#pragma unroll
        for (int nt = 0; nt < 4; ++nt)
          acc[mt][nt] = __builtin_amdgcn_mfma_f32_16x16x32_f16(
              a[mt], b[nt], acc[mt][nt], 0, 0, 0);
    }
    __syncthreads();
  }
  // epilogue: + bi, cvt f16, scatter-store in scan-fragment layout (8B stores)
  const int t_  = blockIdx.y >> 1;   // timestep
  const int bhf = blockIdx.y & 1;    // batch half (blk 0-7 vs 8-15)
  const int gg  = blockIdx.x >> 1;   // gate (r/z/n)
  const int xh  = blockIdx.x & 1;    // gate-col half (wave 0-3 vs 4-7)
  float biv[4];
#pragma unroll
  for (int nt = 0; nt < 4; ++nt) biv[nt] = bi[n0 + wn * 64 + nt * 16 + (lane & 15)];
#pragma unroll
  for (int mt = 0; mt < 4; ++mt) {
    const int blk = bhf * 8 + wm * 4 + mt;
#pragma unroll
    for (int nt = 0; nt < 4; ++nt) {
      const int w = xh * 4 + wn * 2 + (nt >> 1);
      const int vecidx = ((t_ * 16 + blk) * 8 + w) * 6 + gg * 2 + (nt & 1);
      f16x4 hv;
#pragma unroll
      for (int r = 0; r < 4; ++r) hv[r] = (f16)(acc[mt][nt][r] + biv[nt]);
      *reinterpret_cast<f16x4*>(gx + (size_t)vecidx * 256 + lane * 4) = hv;
    }
  }
}

// ---------------- K2: GRU scan + fused head, 16 blocks x 8 waves ------------
// block = 16 batch rows; wave owns 32 H-cols per gate. r,z Wh frags in regs,
// n frags in LDS, Wo frags in LDS. h kept as ready-made MFMA A-fragments in
// LDS (double buffer, granule swizzle p = g ^ (g>>3): conflict-free on both
// read and write). gx (read-only) prefetched one step ahead as 6x f16x4.
// Head (h_t @ Wo -> out[t-1]) computed by wave 0 each step.
__global__ __launch_bounds__(512, 2) void k_scan(
    const float* __restrict__ carry0, const float* __restrict__ Wh,
    const float* __restrict__ bhn, const f16* __restrict__ gxL,
    const float* __restrict__ Wo, const float* __restrict__ bo,
    float* __restrict__ out) {
  __shared__ f16 nfr[8 * 2 * 8 * 64 * 8];  // 131072 B: n-gate B-frags
  __shared__ f16 ha[2 * 8 * 64 * 8];       // 16384 B: h A-frag double buffer
  __shared__ f16 wofs[8 * 64 * 8];         // 8192 B: Wo B-frags
  const int tid = threadIdx.x;
  const int lane = tid & 63;
  const int wave = tid >> 6;  // 0..7
  const int l15 = lane & 15, l4 = lane >> 4;
  const int r0 = blockIdx.x * 16;

  // Wh gates r(0), z(1) -> register fragments (B[k][j]: j=lane&15,
  // k = kt*32 + (lane>>4)*8 + e)
  f16x8 whf[2][2][8];
#pragma unroll
  for (int g = 0; g < 2; ++g)
#pragma unroll
    for (int nt = 0; nt < 2; ++nt) {
      const int col = g * 256 + wave * 32 + nt * 16 + l15;
#pragma unroll
      for (int kt = 0; kt < 8; ++kt)
#pragma unroll
        for (int e = 0; e < 8; ++e)
          whf[g][nt][kt][e] = (f16)Wh[(size_t)(kt * 32 + l4 * 8 + e) * 768 + col];
    }
  // n gate -> LDS fragments (frag-linear: conflict-free b128)
#pragma unroll
  for (int nt = 0; nt < 2; ++nt) {
    const int col = 512 + wave * 32 + nt * 16 + l15;
#pragma unroll
    for (int kt = 0; kt < 8; ++kt) {
      f16x8 v;
#pragma unroll
      for (int e = 0; e < 8; ++e)
        v[e] = (f16)Wh[(size_t)(kt * 32 + l4 * 8 + e) * 768 + col];
      *reinterpret_cast<f16x8*>(reinterpret_cast<char*>(nfr) +
                                ((wave * 2 + nt) * 8 + kt) * 1024 + lane * 16) = v;
    }
  }
  // Wo -> LDS B-frags; wave w writes frame kt=w
  {
    f16x8 v;
#pragma unroll
    for (int e = 0; e < 8; ++e)
      v[e] = (f16)Wo[(wave * 32 + l4 * 8 + e) * 16 + l15];
    *reinterpret_cast<f16x8*>(reinterpret_cast<char*>(wofs) + wave * 1024 +
                              lane * 16) = v;
  }
  float bh[2];
#pragma unroll
  for (int nt = 0; nt < 2; ++nt) bh[nt] = bhn[wave * 32 + nt * 16 + l15];
  const float bov = bo[l15];

  // init h_0: registers (C-layout ownership) + A-frags in buffer 0
  float hcur[2][4];
#pragma unroll
  for (int nt = 0; nt < 2; ++nt) {
    const int s = nt * 2 + (l15 >> 3);
#pragma unroll
    for (int j = 0; j < 4; ++j) {
      const int r = l4 * 4 + j;
      const int c = wave * 32 + nt * 16 + l15;
      float h = carry0[(size_t)(r0 + r) * 256 + c];
      hcur[nt][j] = h;
      const int gl = s * 16 + r;
      const int p = gl ^ (gl >> 3);
      *reinterpret_cast<f16*>(reinterpret_cast<char*>(ha) + wave * 1024 + p * 16 +
                              (l15 & 7) * 2) = (f16)h;
    }
  }
  __syncthreads();

  // gx base for this (block, wave): 6 vectors of 256 f16 per step
  const f16* gp0 = gxL + ((size_t)blockIdx.x * 8 + wave) * 1536 + lane * 4;
  f16x4 gv[6], gvn[6];
#pragma unroll
  for (int i = 0; i < 6; ++i)
    gv[i] = *reinterpret_cast<const f16x4*>(gp0 + i * 256);

  const int rdoff = (lane ^ (lane >> 3)) * 16;  // swizzled A-frag read offset

  for (int t = 0; t < 512; ++t) {
    const int cur = (t & 1) * 8192;
    const int nxt = 8192 - cur;

    // prefetch NEXT step's gx (full step of latency cover)
    {
      const f16* gpn = gp0 + (size_t)(t < 511 ? t + 1 : t) * 196608;
#pragma unroll
      for (int i = 0; i < 6; ++i)
        gvn[i] = *reinterpret_cast<const f16x4*>(gpn + i * 256);
    }

    f32x4 acc[3][2] = {};
#pragma unroll
    for (int kt = 0; kt < 8; ++kt) {
      f16x8 a = *reinterpret_cast<const f16x8*>(
          reinterpret_cast<const char*>(ha) + cur + kt * 1024 + rdoff);
#pragma unroll
      for (int nt = 0; nt < 2; ++nt) {
        f16x8 nb = *reinterpret_cast<const f16x8*>(
            reinterpret_cast<const char*>(nfr) + ((wave * 2 + nt) * 8 + kt) * 1024 +
            lane * 16);
        acc[0][nt] = __builtin_amdgcn_mfma_f32_16x16x32_f16(a, whf[0][nt][kt],
                                                            acc[0][nt], 0, 0, 0);
        acc[1][nt] = __builtin_amdgcn_mfma_f32_16x16x32_f16(a, whf[1][nt][kt],
                                                            acc[1][nt], 0, 0, 0);
        acc[2][nt] = __builtin_amdgcn_mfma_f32_16x16x32_f16(a, nb, acc[2][nt], 0, 0, 0);
      }
    }

    // fused head on wave 0: out[t-1] = h_t @ Wo (+bo, clip+exp on std half)
    if (wave == 0) {
      f32x4 aco = {};
#pragma unroll
      for (int kt = 0; kt < 8; ++kt) {
        f16x8 a = *reinterpret_cast<const f16x8*>(
            reinterpret_cast<const char*>(ha) + cur + kt * 1024 + rdoff);
        f16x8 wb = *reinterpret_cast<const f16x8*>(
            reinterpret_cast<const char*>(wofs) + kt * 1024 + lane * 16);
        aco = __builtin_amdgcn_mfma_f32_16x16x32_f16(a, wb, aco, 0, 0, 0);
      }
      if (t > 0) {
#pragma unroll
        for (int r = 0; r < 4; ++r) {
          float y = aco[r] + bov;
          if (l15 >= 8) y = __expf(fminf(fmaxf(y, -20.0f), 2.0f));
          out[((size_t)(t - 1) * 256 + r0 + l4 * 4 + r) * 16 + l15] = y;
        }
      }
    }

    // elementwise GRU + write h_{t+1} A-frags into next buffer
#pragma unroll
    for (int nt = 0; nt < 2; ++nt) {
      const int s = nt * 2 + (l15 >> 3);
#pragma unroll
      for (int j = 0; j < 4; ++j) {
        const int r = l4 * 4 + j;
        float rg = sigm((float)gv[nt][j] + acc[0][nt][j]);
        float zg = sigm((float)gv[2 + nt][j] + acc[1][nt][j]);
        float ng = tanh_fast((float)gv[4 + nt][j] + rg * (acc[2][nt][j] + bh[nt]));
        float h = ng + zg * (hcur[nt][j] - ng);
        hcur[nt][j] = h;
        const int gl = s * 16 + r;
        const int p = gl ^ (gl >> 3);
        *reinterpret_cast<f16*>(reinterpret_cast<char*>(ha) + nxt + wave * 1024 +
                                p * 16 + (l15 & 7) * 2) = (f16)h;
      }
    }
#pragma unroll
    for (int i = 0; i < 6; ++i) gv[i] = gvn[i];
    __syncthreads();
  }

  // final head: out[511] = h_512 @ Wo  (h_512 lives in buffer 0)
  if (wave == 0) {
    f32x4 aco = {};
#pragma unroll
    for (int kt = 0; kt < 8; ++kt) {
      f16x8 a = *reinterpret_cast<const f16x8*>(
          reinterpret_cast<const char*>(ha) + kt * 1024 + rdoff);
      f16x8 wb = *reinterpret_cast<const f16x8*>(
          reinterpret_cast<const char*>(wofs) + kt * 1024 + lane * 16);
      aco = __builtin_amdgcn_mfma_f32_16x16x32_f16(a, wb, aco, 0, 0, 0);
    }
#pragma unroll
    for (int r = 0; r < 4; ++r) {
      float y = aco[r] + bov;
      if (l15 >= 8) y = __expf(fminf(fmaxf(y, -20.0f), 2.0f));
      out[((size_t)511 * 256 + r0 + l4 * 4 + r) * 16 + l15] = y;
    }
  }
}

extern "C" void kernel_launch(void* const* d_in, const int* in_sizes, int n_in,
                              void* d_out, int out_size, void* d_ws, size_t ws_size,
                              hipStream_t stream) {
  const float* x      = (const float*)d_in[0];
  const float* carry0 = (const float*)d_in[1];
  const float* Wi     = (const float*)d_in[2];
  const float* bi     = (const float*)d_in[3];
  const float* Wh     = (const float*)d_in[4];
  const float* bhn    = (const float*)d_in[5];
  const float* Wo     = (const float*)d_in[6];
  const float* bo     = (const float*)d_in[7];
  float* out = (float*)d_out;

  f16* gx  = (f16*)d_ws;                       // 512*256*768 f16 = 192 MiB
  f16* WiT = gx + (size_t)512 * 256 * 768;     // 768*256 f16

  k_prep_wit<<<dim3(768), dim3(256), 0, stream>>>(Wi, WiT);
  k_gemm_gx<<<dim3(6, 1024), dim3(256), 0, stream>>>(x, WiT, bi, gx);
  k_scan<<<dim3(16), dim3(512), 0, stream>>>(carry0, Wh, bhn, gx, Wo, bo, out);
}